// Round 17
// baseline (58.407 us; speedup 1.0000x reference)
//
#include <hip/hip_runtime.h>
#include <cstdint>

#define NCOARSE 4000
#define NFINE   40000
#define DIM     128
#define GRES    8
#define CELLH   0.125f
#define FCAP    384      // flat candidate-list region per home cell
#define NB_B    128      // flat-list blocks (4 home cells each)
#define NB_Y    125      // Y-GEMM blocks (32 rows each)
#define NBUILD  (NB_B + NB_Y)   // 253
#define LPP     8        // lanes per fine point

__device__ __forceinline__ uint64_t min64(uint64_t a, uint64_t b) { return a < b ? a : b; }
__device__ __forceinline__ uint64_t max64(uint64_t a, uint64_t b) { return a > b ? a : b; }
__device__ __forceinline__ int cell_coord(float x) {
    int c = (int)(x * 8.0f);
    return c < 0 ? 0 : (c > 7 ? 7 : c);
}

// ---- build: ring-ordered (inner/outer) flat candidate lists + Y = xc @ W ----
union BuildSM {
    uint16_t cellS[4096];    // 8 KB  (flat-list part)
    float    xs[32][DIM];    // 16 KB (Y-GEMM part)
};

__global__ __launch_bounds__(256) void k_build(const float* __restrict__ pc,
                                               const float* __restrict__ xc,
                                               const float* __restrict__ W,
                                               int*    __restrict__ nbrCnt,
                                               float4* __restrict__ flatC,
                                               float*  __restrict__ Y) {
    __shared__ BuildSM sm;
    const int bid = blockIdx.x, tid = threadIdx.x;

    if (bid < NB_B) {
        // stage all 4000 cell ids
        #pragma unroll
        for (int t = 0; t < 16; ++t) {
            const int idx = t * 256 + tid;
            uint16_t cv = 0xFFFF;
            if (idx < NCOARSE)
                cv = (uint16_t)((cell_coord(pc[3*idx+2]) << 6) |
                                (cell_coord(pc[3*idx+1]) << 3) |
                                 cell_coord(pc[3*idx]));
            sm.cellS[idx] = cv;
        }
        __syncthreads();
        const int wid = tid >> 6, lane = tid & 63;
        const int hc = bid * 4 + wid;
        const int hx = hc & 7, hy = (hc >> 3) & 7, hz = hc >> 6;
        const int bx0 = max(hx-1,0), bx1 = min(hx+1,7);
        const int by0 = max(hy-1,0), by1 = min(hy+1,7);
        const int bz0 = max(hz-1,0), bz1 = min(hz+1,7);
        int offIn = 0, offOut = 0;
        for (int it = 0; it < 63; ++it) {
            const int j = it * 64 + lane;
            const uint16_t cid = sm.cellS[j];
            const int cx = cid & 7, cy = (cid >> 3) & 7, cz = cid >> 6;
            const bool inBox = (j < NCOARSE) && cx >= bx0 && cx <= bx1 &&
                               cy >= by0 && cy <= by1 && cz >= bz0 && cz <= bz1;
            const int man = abs(cx - hx) + abs(cy - hy) + abs(cz - hz);
            const bool isIn  = inBox && (man <= 1);   // home + face-adjacent
            const bool isOut = inBox && (man >= 2);   // edge + corner cells
            const unsigned long long mIn  = __ballot(isIn);
            const unsigned long long mOut = __ballot(isOut);
            if (isIn) {
                const int d = offIn + (int)__popcll(mIn & ((1ull << lane) - 1ull));
                if (d < FCAP)
                    flatC[hc * FCAP + d] =
                        make_float4(pc[3*j], pc[3*j+1], pc[3*j+2], __int_as_float(j));
            }
            if (isOut) {
                const int r = offOut + (int)__popcll(mOut & ((1ull << lane) - 1ull));
                const int d = FCAP - 1 - r;           // outer grows from the back
                if (d >= 0)
                    flatC[hc * FCAP + d] =
                        make_float4(pc[3*j], pc[3*j+1], pc[3*j+2], __int_as_float(j));
            }
            offIn  += (int)__popcll(mIn);
            offOut += (int)__popcll(mOut);
        }
        if (lane == 0) nbrCnt[hc] = offIn | (offOut << 16);   // write-once
    } else {
        // Y-GEMM tile: 32 rows x 128 cols
        const int g  = bid - NB_B;
        const int r0 = g * 32;
        #pragma unroll
        for (int t = 0; t < 4; ++t)
            reinterpret_cast<float4*>(sm.xs)[tid + t * 256] =
                reinterpret_cast<const float4*>(xc + r0 * DIM)[tid + t * 256];
        __syncthreads();
        const int rq = tid >> 5;
        const int jq = tid & 31;
        float acc[4][4];
        #pragma unroll
        for (int i = 0; i < 4; ++i)
            #pragma unroll
            for (int j = 0; j < 4; ++j) acc[i][j] = 0.f;
        #pragma unroll 2
        for (int k = 0; k < DIM; ++k) {
            const float4 wv = *reinterpret_cast<const float4*>(W + k * DIM + jq * 4);
            #pragma unroll
            for (int i = 0; i < 4; ++i) {
                const float a = sm.xs[rq + 8 * i][k];
                acc[i][0] += a * wv.x; acc[i][1] += a * wv.y;
                acc[i][2] += a * wv.z; acc[i][3] += a * wv.w;
            }
        }
        #pragma unroll
        for (int i = 0; i < 4; ++i)
            *reinterpret_cast<float4*>(Y + (r0 + rq + 8 * i) * DIM + jq * 4) =
                make_float4(acc[i][0], acc[i][1], acc[i][2], acc[i][3]);
    }
}

// ---- main: two-segment guarded-scan KNN + gather-mean of Y ----
__device__ __forceinline__ void popmin_merge(const uint64_t own[7], uint64_t mg[7]) {
    uint64_t a0 = own[0], a1 = own[1], a2 = own[2], a3 = own[3],
             a4 = own[4], a5 = own[5], a6 = own[6];
    #pragma unroll
    for (int r = 0; r < 7; ++r) {
        uint64_t m = a0;
        m = min64(m, __shfl_xor((unsigned long long)m, 1));
        m = min64(m, __shfl_xor((unsigned long long)m, 2));
        m = min64(m, __shfl_xor((unsigned long long)m, 4));
        mg[r] = m;
        const bool win = (a0 == m);      // unique keys -> one winner
        a0 = win ? a1 : a0;
        a1 = win ? a2 : a1;
        a2 = win ? a3 : a2;
        a3 = win ? a4 : a3;
        a4 = win ? a5 : a4;
        a5 = win ? a6 : a5;
        a6 = win ? ~0ull : a6;
    }
}

__device__ __forceinline__ bool done_check(uint64_t k7, float fx, float fy, float fz,
                                           int ix, int iy, int iz, int s) {
    const float d7 = __uint_as_float((uint32_t)(k7 >> 32));
    float clear = 1e30f;
    if (ix - s >= 0) clear = fminf(clear, __fsub_rn(fx, (float)(ix - s) * CELLH));
    if (ix + s <= 6) clear = fminf(clear, __fsub_rn((float)(ix + s + 1) * CELLH, fx));
    if (iy - s >= 0) clear = fminf(clear, __fsub_rn(fy, (float)(iy - s) * CELLH));
    if (iy + s <= 6) clear = fminf(clear, __fsub_rn((float)(iy + s + 1) * CELLH, fy));
    if (iz - s >= 0) clear = fminf(clear, __fsub_rn(fz, (float)(iz - s) * CELLH));
    if (iz + s <= 6) clear = fminf(clear, __fsub_rn((float)(iz + s + 1) * CELLH, fz));
    return d7 < clear * clear * 0.9999f;   // NaN sentinel -> false
}

#define INS(p) { \
    const float ddx = __fsub_rn(fx, (p).x); \
    const float ddy = __fsub_rn(fy, (p).y); \
    const float ddz = __fsub_rn(fz, (p).z); \
    const float d2  = __fadd_rn(__fadd_rn(__fmul_rn(ddx, ddx), __fmul_rn(ddy, ddy)), \
                                __fmul_rn(ddz, ddz)); \
    const uint64_t v = ((uint64_t)__float_as_uint(d2) << 32) | (uint32_t)__float_as_uint((p).w); \
    if (v < own[6]) { \
        own[6] = min64(own[6], max64(own[5], v)); \
        own[5] = min64(own[5], max64(own[4], v)); \
        own[4] = min64(own[4], max64(own[3], v)); \
        own[3] = min64(own[3], max64(own[2], v)); \
        own[2] = min64(own[2], max64(own[1], v)); \
        own[1] = min64(own[1], max64(own[0], v)); \
        own[0] = min64(own[0], v); \
    } }

#define BRUTE() { \
    _Pragma("unroll") \
    for (int r = 0; r < 7; ++r) own[r] = ~0ull; \
    for (int i = par; i < NCOARSE; i += LPP) { \
        const float4 p = make_float4(pc[3*i], pc[3*i+1], pc[3*i+2], __int_as_float(i)); \
        INS(p) \
    } }

__global__ __launch_bounds__(256) void k_main(
    const float*  __restrict__ Y,        // [4000][128] = xc @ W
    const float*  __restrict__ bias,
    const int*    __restrict__ nbrCnt,   // packed: nin | nout<<16
    const float4* __restrict__ flatC,    // [0,nin) inner, [FCAP-nout,FCAP) outer
    const float*  __restrict__ pc,       // raw coarse positions (brute fallback)
    const float*  __restrict__ pf,
    float* __restrict__ out)
{
    const int tid = threadIdx.x;
    const int fl  = tid >> 3;        // 0..31 local fine point
    const int par = tid & 7;         // lane within point-octet
    const int f   = blockIdx.x * 32 + fl;

    const float fx = pf[3*f], fy = pf[3*f+1], fz = pf[3*f+2];
    const int ix = cell_coord(fx), iy = cell_coord(fy), iz = cell_coord(fz);
    const int cell = (iz << 6) | (iy << 3) | ix;

    const int packed = nbrCnt[cell];
    const int nin  = packed & 0xFFFF;
    const int nout = packed >> 16;
    const int total = nin + nout;

    uint64_t own[7];
    #pragma unroll
    for (int r = 0; r < 7; ++r) own[r] = ~0ull;
    uint64_t mg[7];

    if (total <= FCAP) {
        const float4* fpts = flatC + cell * FCAP;
        // segment A: home + face cells (top-7 hits concentrate here; lists warm up)
        for (int i = par; i < nin; i += LPP) { const float4 p = fpts[i]; INS(p) }
        // segment B: edge/corner cells (guard now warm -> most skip after one cmp)
        const float4* bpts = fpts + (FCAP - nout);
        for (int i = par; i < nout; i += LPP) { const float4 p = bpts[i]; INS(p) }
        popmin_merge(own, mg);
        if (!done_check(mg[6], fx, fy, fz, ix, iy, iz, 1)) {   // ~never (P<1e-9/pt)
            BRUTE();
            popmin_merge(own, mg);
        }
    } else {                                     // flat region overflowed (~never)
        BRUTE();
        popmin_merge(own, mg);
    }

    // 6th/7th sqrt tie repair (reference sorts by f32 sqrt, stable) — uniform per octet
    int i5 = (int)(uint32_t)mg[5];
    {
        const int i6 = (int)(uint32_t)mg[6];
        const float d5 = sqrtf(__uint_as_float((uint32_t)(mg[5] >> 32)));
        const float d6 = sqrtf(__uint_as_float((uint32_t)(mg[6] >> 32)));
        if (d5 == d6 && i6 < i5) i5 = i6;
    }
    const int id0 = (int)(uint32_t)mg[0];
    const int id1 = (int)(uint32_t)mg[1];
    const int id2 = (int)(uint32_t)mg[2];
    const int id3 = (int)(uint32_t)mg[3];
    const int id4 = (int)(uint32_t)mg[4];
    const int id5 = i5;

    // epilogue: out[f] = mean(Y[idx6]) + b ; lane par covers 16 dims
    constexpr float inv6 = 1.0f / 6.0f;
    #pragma unroll
    for (int k = 0; k < 4; ++k) {
        const int q = (k * 8 + par) * 4;
        const float4 y0 = *reinterpret_cast<const float4*>(Y + id0 * DIM + q);
        const float4 y1 = *reinterpret_cast<const float4*>(Y + id1 * DIM + q);
        const float4 y2 = *reinterpret_cast<const float4*>(Y + id2 * DIM + q);
        const float4 y3 = *reinterpret_cast<const float4*>(Y + id3 * DIM + q);
        const float4 y4 = *reinterpret_cast<const float4*>(Y + id4 * DIM + q);
        const float4 y5 = *reinterpret_cast<const float4*>(Y + id5 * DIM + q);
        const float4 bv = *reinterpret_cast<const float4*>(bias + q);
        float4 o;
        o.x = (y0.x + y1.x + y2.x + y3.x + y4.x + y5.x) * inv6 + bv.x;
        o.y = (y0.y + y1.y + y2.y + y3.y + y4.y + y5.y) * inv6 + bv.y;
        o.z = (y0.z + y1.z + y2.z + y3.z + y4.z + y5.z) * inv6 + bv.z;
        o.w = (y0.w + y1.w + y2.w + y3.w + y4.w + y5.w) * inv6 + bv.w;
        *reinterpret_cast<float4*>(out + f * DIM + q) = o;
    }
}

extern "C" void kernel_launch(void* const* d_in, const int* in_sizes, int n_in,
                              void* d_out, int out_size, void* d_ws, size_t ws_size,
                              hipStream_t stream) {
    const float* xc = (const float*)d_in[0];
    const float* pc = (const float*)d_in[1];
    const float* pf = (const float*)d_in[2];
    const float* W  = (const float*)d_in[3];
    const float* b  = (const float*)d_in[4];
    float* out = (float*)d_out;

    // ws layout (bytes):
    //   0        nbrCnt  512 ints (2048, pad to 4096)
    //   4096     flatC   512*384 float4 (3145728)
    //   3149824  Y       4000*128 f32   (2048000)   total 5197824
    int*    nbrCnt = (int*)d_ws;
    float4* flatC  = (float4*)((char*)d_ws + 4096);
    float*  Y      = (float*)((char*)d_ws + 3149824);

    k_build<<<dim3(NBUILD),          dim3(256), 0, stream>>>(pc, xc, W, nbrCnt, flatC, Y);
    k_main <<<dim3(NFINE / 32),      dim3(256), 0, stream>>>(Y, b, nbrCnt, flatC, pc, pf, out);
}

// Round 18
// 48.718 us; speedup vs baseline: 1.1989x; 1.1989x over previous
//
#include <hip/hip_runtime.h>
#include <cstdint>

#define NCOARSE 4000
#define NFINE   40000
#define DIM     128
#define GRES    8
#define CELLH   0.125f
#define SUBH    0.0625f
#define MCAP    384      // parent 27-box member cap
#define FCAP2   192      // pruned per-subcell list cap (lambda~103)
#define NB_S    1024     // subcell blocks: parent = bid>>1, 4 subcells/block
#define NB_Y    125      // Y-GEMM blocks (32 rows each)
#define NBUILD  (NB_S + NB_Y)   // 1149
#define LPP     8        // lanes per fine point in k_main

__device__ __forceinline__ uint64_t min64(uint64_t a, uint64_t b) { return a < b ? a : b; }
__device__ __forceinline__ uint64_t max64(uint64_t a, uint64_t b) { return a > b ? a : b; }
__device__ __forceinline__ int cell_coord(float x) {
    int c = (int)(x * 8.0f);
    return c < 0 ? 0 : (c > 7 ? 7 : c);
}
__device__ __forceinline__ int cell16(float x) {
    int c = (int)(x * 16.0f);
    return c < 0 ? 0 : (c > 15 ? 15 : c);
}

// ---------------- build: pruned per-subcell lists + Y = xc @ W ----------------
union BuildSM {
    struct {
        uint16_t cellS[4096];     // 8 KB
        uint16_t memberIdx[MCAP]; // 768 B
        int mcount, mflag;
    } l;
    float xs[32][DIM];            // 16 KB (Y-GEMM part)
};

__global__ __launch_bounds__(256) void k_build(const float* __restrict__ pc,
                                               const float* __restrict__ xc,
                                               const float* __restrict__ W,
                                               int*    __restrict__ nbrCnt,   // [4096]
                                               float*  __restrict__ Rarr,     // [4096]
                                               float4* __restrict__ flatS,    // [4096][FCAP2]
                                               float*  __restrict__ Y) {
    __shared__ BuildSM sm;
    const int bid = blockIdx.x, tid = threadIdx.x;

    if (bid < NB_S) {
        // stage all 4000 coarse cell ids (8^3 grid)
        #pragma unroll
        for (int t = 0; t < 16; ++t) {
            const int idx = t * 256 + tid;
            uint16_t cv = 0xFFFF;
            if (idx < NCOARSE)
                cv = (uint16_t)((cell_coord(pc[3*idx+2]) << 6) |
                                (cell_coord(pc[3*idx+1]) << 3) |
                                 cell_coord(pc[3*idx]));
            sm.l.cellS[idx] = cv;
        }
        __syncthreads();

        const int wid = tid >> 6, lane = tid & 63;
        const int parent = bid >> 1;
        const int px = parent & 7, py = (parent >> 3) & 7, pz = parent >> 6;
        const int bx0 = max(px-1,0), bx1 = min(px+1,7);
        const int by0 = max(py-1,0), by1 = min(py+1,7);
        const int bz0 = max(pz-1,0), bz1 = min(pz+1,7);

        // wave 0: collect the parent's 27-box members once for the block
        if (wid == 0) {
            int off = 0;
            for (int it = 0; it < 63; ++it) {
                const int j = it * 64 + lane;
                const uint16_t cid = sm.l.cellS[j];
                const int cx = cid & 7, cy = (cid >> 3) & 7, cz = cid >> 6;
                const bool in = (j < NCOARSE) && cx >= bx0 && cx <= bx1 &&
                                cy >= by0 && cy <= by1 && cz >= bz0 && cz <= bz1;
                const unsigned long long mask = __ballot(in);
                if (in) {
                    const int d = off + (int)__popcll(mask & ((1ull << lane) - 1ull));
                    if (d < MCAP) sm.l.memberIdx[d] = (uint16_t)j;
                }
                off += (int)__popcll(mask);
            }
            if (lane == 0) { sm.l.mcount = min(off, MCAP); sm.l.mflag = (off > MCAP); }
        }
        __syncthreads();

        const int  mcount = sm.l.mcount;
        const bool mflag  = sm.l.mflag != 0;

        // each wave: one subcell of this parent
        const int s  = (bid & 1) * 4 + wid;
        const int gx = px * 2 + (s & 1);
        const int gy = py * 2 + ((s >> 1) & 1);
        const int gz = pz * 2 + (s >> 2);
        const int SIDX = (gz << 8) | (gy << 4) | gx;
        const float scx = ((float)gx + 0.5f) * SUBH;
        const float scy = ((float)gy + 0.5f) * SUBH;
        const float scz = ((float)gz + 0.5f) * SUBH;

        // per-lane top-7 by distance-to-subcenter over the members
        uint64_t own[7];
        #pragma unroll
        for (int r = 0; r < 7; ++r) own[r] = ~0ull;
        for (int i = lane; i < mcount; i += 64) {
            const int j = (int)sm.l.memberIdx[i];
            const float dx = pc[3*j]   - scx;
            const float dy = pc[3*j+1] - scy;
            const float dz = pc[3*j+2] - scz;
            const float d2 = dx*dx + dy*dy + dz*dz;
            const uint64_t v = ((uint64_t)__float_as_uint(d2) << 32) | (uint32_t)j;
            if (v < own[6]) {
                own[6] = min64(own[6], max64(own[5], v));
                own[5] = min64(own[5], max64(own[4], v));
                own[4] = min64(own[4], max64(own[3], v));
                own[3] = min64(own[3], max64(own[2], v));
                own[2] = min64(own[2], max64(own[1], v));
                own[1] = min64(own[1], max64(own[0], v));
                own[0] = min64(own[0], v);
            }
        }
        // 7-round pop-min across 64 lanes -> 7th-smallest center distance
        uint64_t a0=own[0],a1=own[1],a2=own[2],a3=own[3],a4=own[4],a5=own[5],a6=own[6];
        uint64_t d7key = ~0ull;
        #pragma unroll
        for (int r = 0; r < 7; ++r) {
            uint64_t m = a0;
            m = min64(m, __shfl_xor((unsigned long long)m, 1));
            m = min64(m, __shfl_xor((unsigned long long)m, 2));
            m = min64(m, __shfl_xor((unsigned long long)m, 4));
            m = min64(m, __shfl_xor((unsigned long long)m, 8));
            m = min64(m, __shfl_xor((unsigned long long)m, 16));
            m = min64(m, __shfl_xor((unsigned long long)m, 32));
            d7key = m;
            const bool win = (a0 == m);
            a0 = win ? a1 : a0; a1 = win ? a2 : a1; a2 = win ? a3 : a2;
            a3 = win ? a4 : a3; a4 = win ? a5 : a4; a5 = win ? a6 : a5;
            a6 = win ? ~0ull : a6;
        }
        const float d7c = sqrtf(__uint_as_float((uint32_t)(d7key >> 32)));

        // clearance of subcenter to the parent box's interior boundary
        float clear = 1e30f;
        if (bx0 > 0) clear = fminf(clear, scx - (float)bx0 * CELLH);
        if (bx1 < 7) clear = fminf(clear, (float)(bx1+1) * CELLH - scx);
        if (by0 > 0) clear = fminf(clear, scy - (float)by0 * CELLH);
        if (by1 < 7) clear = fminf(clear, (float)(by1+1) * CELLH - scy);
        if (bz0 > 0) clear = fminf(clear, scz - (float)bz0 * CELLH);
        if (bz1 < 7) clear = fminf(clear, (float)(bz1+1) * CELLH - scz);

        bool ok = (d7c < clear * 0.9999f) && !mflag && (mcount >= 7);  // NaN -> false
        const float R  = d7c * 1.0001f + 0.1082533f + 1e-5f;  // d7c + 2*half-diag + margins
        const float R2 = R * R;

        // emit members within the ball
        int off2 = 0;
        for (int i = lane; i < mcount; i += 64) {
            const int j = (int)sm.l.memberIdx[i];
            const float x = pc[3*j], y = pc[3*j+1], z = pc[3*j+2];
            const float dx = x - scx, dy = y - scy, dz = z - scz;
            const bool in = (dx*dx + dy*dy + dz*dz) <= R2;
            const unsigned long long mask = __ballot(in);
            if (in) {
                const int d = off2 + (int)__popcll(mask & ((1ull << lane) - 1ull));
                if (d < FCAP2)
                    flatS[SIDX * FCAP2 + d] = make_float4(x, y, z, __int_as_float(j));
            }
            off2 += (int)__popcll(mask);
        }
        ok = ok && (off2 <= FCAP2) && (off2 >= 7);
        if (lane == 0) {
            nbrCnt[SIDX] = ok ? off2 : 0x40000000;   // flag -> BRUTE in k_main
            Rarr[SIDX]   = R;
        }
    } else {
        // Y-GEMM tile: 32 rows x 128 cols
        const int g  = bid - NB_S;
        const int r0 = g * 32;
        #pragma unroll
        for (int t = 0; t < 4; ++t)
            reinterpret_cast<float4*>(sm.xs)[tid + t * 256] =
                reinterpret_cast<const float4*>(xc + r0 * DIM)[tid + t * 256];
        __syncthreads();
        const int rq = tid >> 5;
        const int jq = tid & 31;
        float acc[4][4];
        #pragma unroll
        for (int i = 0; i < 4; ++i)
            #pragma unroll
            for (int j = 0; j < 4; ++j) acc[i][j] = 0.f;
        #pragma unroll 2
        for (int k = 0; k < DIM; ++k) {
            const float4 wv = *reinterpret_cast<const float4*>(W + k * DIM + jq * 4);
            #pragma unroll
            for (int i = 0; i < 4; ++i) {
                const float a = sm.xs[rq + 8 * i][k];
                acc[i][0] += a * wv.x; acc[i][1] += a * wv.y;
                acc[i][2] += a * wv.z; acc[i][3] += a * wv.w;
            }
        }
        #pragma unroll
        for (int i = 0; i < 4; ++i)
            *reinterpret_cast<float4*>(Y + (r0 + rq + 8 * i) * DIM + jq * 4) =
                make_float4(acc[i][0], acc[i][1], acc[i][2], acc[i][3]);
    }
}

// ---------------- main: pruned-list KNN + gather-mean of Y ----------------
__device__ __forceinline__ void popmin_merge(const uint64_t own[7], uint64_t mg[7]) {
    uint64_t a0 = own[0], a1 = own[1], a2 = own[2], a3 = own[3],
             a4 = own[4], a5 = own[5], a6 = own[6];
    #pragma unroll
    for (int r = 0; r < 7; ++r) {
        uint64_t m = a0;
        m = min64(m, __shfl_xor((unsigned long long)m, 1));
        m = min64(m, __shfl_xor((unsigned long long)m, 2));
        m = min64(m, __shfl_xor((unsigned long long)m, 4));
        mg[r] = m;
        const bool win = (a0 == m);      // unique keys -> one winner
        a0 = win ? a1 : a0; a1 = win ? a2 : a1; a2 = win ? a3 : a2;
        a3 = win ? a4 : a3; a4 = win ? a5 : a4; a5 = win ? a6 : a5;
        a6 = win ? ~0ull : a6;
    }
}

#define INS(p) { \
    const float ddx = __fsub_rn(fx, (p).x); \
    const float ddy = __fsub_rn(fy, (p).y); \
    const float ddz = __fsub_rn(fz, (p).z); \
    const float d2  = __fadd_rn(__fadd_rn(__fmul_rn(ddx, ddx), __fmul_rn(ddy, ddy)), \
                                __fmul_rn(ddz, ddz)); \
    const uint64_t v = ((uint64_t)__float_as_uint(d2) << 32) | (uint32_t)__float_as_uint((p).w); \
    if (v < own[6]) { \
        own[6] = min64(own[6], max64(own[5], v)); \
        own[5] = min64(own[5], max64(own[4], v)); \
        own[4] = min64(own[4], max64(own[3], v)); \
        own[3] = min64(own[3], max64(own[2], v)); \
        own[2] = min64(own[2], max64(own[1], v)); \
        own[1] = min64(own[1], max64(own[0], v)); \
        own[0] = min64(own[0], v); \
    } }

#define BRUTE() { \
    _Pragma("unroll") \
    for (int r = 0; r < 7; ++r) own[r] = ~0ull; \
    for (int i = par; i < NCOARSE; i += LPP) { \
        const float4 p = make_float4(pc[3*i], pc[3*i+1], pc[3*i+2], __int_as_float(i)); \
        INS(p) \
    } }

__global__ __launch_bounds__(256) void k_main(
    const float*  __restrict__ Y,        // [4000][128] = xc @ W
    const float*  __restrict__ bias,
    const int*    __restrict__ nbrCnt,   // [4096] pruned counts (or flag)
    const float*  __restrict__ Rarr,     // [4096] pruning radii
    const float4* __restrict__ flatS,    // [4096][FCAP2]
    const float*  __restrict__ pc,       // raw coarse positions (brute fallback)
    const float*  __restrict__ pf,
    float* __restrict__ out)
{
    const int tid = threadIdx.x;
    const int fl  = tid >> 3;        // 0..31 local fine point
    const int par = tid & 7;         // lane within point-octet
    const int f   = blockIdx.x * 32 + fl;

    const float fx = pf[3*f], fy = pf[3*f+1], fz = pf[3*f+2];
    const int gx = cell16(fx), gy = cell16(fy), gz = cell16(fz);
    const int SIDX = (gz << 8) | (gy << 4) | gx;

    const float scx = ((float)gx + 0.5f) * SUBH;
    const float scy = ((float)gy + 0.5f) * SUBH;
    const float scz = ((float)gz + 0.5f) * SUBH;
    const float ex = fx - scx, ey = fy - scy, ez = fz - scz;
    const float dps = sqrtf(ex*ex + ey*ey + ez*ez) * 1.0001f + 1e-6f;

    const int   n = nbrCnt[SIDX];
    const float R = Rarr[SIDX];

    uint64_t own[7];
    #pragma unroll
    for (int r = 0; r < 7; ++r) own[r] = ~0ull;
    uint64_t mg[7];

    if (n <= FCAP2) {
        const float4* fpts = flatS + SIDX * FCAP2;
        #pragma unroll 2
        for (int i = par; i < n; i += LPP) { const float4 p = fpts[i]; INS(p) }
        popmin_merge(own, mg);
        const float d7u = sqrtf(__uint_as_float((uint32_t)(mg[6] >> 32)));
        // exact by Lipschitz: fires ~never; NaN d7u -> false -> BRUTE
        if (!((d7u + dps) * 1.0002f < R)) {
            BRUTE();
            popmin_merge(own, mg);
        }
    } else {                                     // build flagged this subcell
        BRUTE();
        popmin_merge(own, mg);
    }

    // 6th/7th sqrt tie repair (reference sorts by f32 sqrt, stable) — uniform per octet
    int i5 = (int)(uint32_t)mg[5];
    {
        const int i6 = (int)(uint32_t)mg[6];
        const float d5 = sqrtf(__uint_as_float((uint32_t)(mg[5] >> 32)));
        const float d6 = sqrtf(__uint_as_float((uint32_t)(mg[6] >> 32)));
        if (d5 == d6 && i6 < i5) i5 = i6;
    }
    const int id0 = (int)(uint32_t)mg[0];
    const int id1 = (int)(uint32_t)mg[1];
    const int id2 = (int)(uint32_t)mg[2];
    const int id3 = (int)(uint32_t)mg[3];
    const int id4 = (int)(uint32_t)mg[4];
    const int id5 = i5;

    // epilogue: out[f] = mean(Y[idx6]) + b ; lane par covers 16 dims
    constexpr float inv6 = 1.0f / 6.0f;
    #pragma unroll
    for (int k = 0; k < 4; ++k) {
        const int q = (k * 8 + par) * 4;
        const float4 y0 = *reinterpret_cast<const float4*>(Y + id0 * DIM + q);
        const float4 y1 = *reinterpret_cast<const float4*>(Y + id1 * DIM + q);
        const float4 y2 = *reinterpret_cast<const float4*>(Y + id2 * DIM + q);
        const float4 y3 = *reinterpret_cast<const float4*>(Y + id3 * DIM + q);
        const float4 y4 = *reinterpret_cast<const float4*>(Y + id4 * DIM + q);
        const float4 y5 = *reinterpret_cast<const float4*>(Y + id5 * DIM + q);
        const float4 bv = *reinterpret_cast<const float4*>(bias + q);
        float4 o;
        o.x = (y0.x + y1.x + y2.x + y3.x + y4.x + y5.x) * inv6 + bv.x;
        o.y = (y0.y + y1.y + y2.y + y3.y + y4.y + y5.y) * inv6 + bv.y;
        o.z = (y0.z + y1.z + y2.z + y3.z + y4.z + y5.z) * inv6 + bv.z;
        o.w = (y0.w + y1.w + y2.w + y3.w + y4.w + y5.w) * inv6 + bv.w;
        *reinterpret_cast<float4*>(out + f * DIM + q) = o;
    }
}

extern "C" void kernel_launch(void* const* d_in, const int* in_sizes, int n_in,
                              void* d_out, int out_size, void* d_ws, size_t ws_size,
                              hipStream_t stream) {
    const float* xc = (const float*)d_in[0];
    const float* pc = (const float*)d_in[1];
    const float* pf = (const float*)d_in[2];
    const float* W  = (const float*)d_in[3];
    const float* b  = (const float*)d_in[4];
    float* out = (float*)d_out;

    // ws layout (bytes):
    //   0          nbrCnt  4096 ints  (16384)
    //   16384      Rarr    4096 f32   (16384)
    //   32768      flatS   4096*192 float4 (12582912)
    //   12615680   Y       4000*128 f32    (2048000)   total 14663680
    int*    nbrCnt = (int*)d_ws;
    float*  Rarr   = (float*)((char*)d_ws + 16384);
    float4* flatS  = (float4*)((char*)d_ws + 32768);
    float*  Y      = (float*)((char*)d_ws + 12615680);

    k_build<<<dim3(NBUILD),     dim3(256), 0, stream>>>(pc, xc, W, nbrCnt, Rarr, flatS, Y);
    k_main <<<dim3(NFINE / 32), dim3(256), 0, stream>>>(Y, b, nbrCnt, Rarr, flatS, pc, pf, out);
}